// Round 1
// baseline (646.380 us; speedup 1.0000x reference)
//
#include <hip/hip_runtime.h>
#include <math.h>

// Problem constants (all compile-time from the reference)
#define NB      32      // NUM_BLOCKS = D_HEAD/3
#define NHEADS  8
#define DH      96
#define DT      64
#define HALFT   32
#define BB      2
#define TT      8
#define HH      64
#define WW      64

// ---------------------------------------------------------------------------
// Kernel 1: temporal embedding  temp[b*T+t][d] = emb @ Wt.T + bt
//   emb interleaved: [cos(p*f0), sin(p*f0), cos(p*f1), ...]
// grid = B*T (16), block = 96. Trivial cost; use precise sincosf.
// ---------------------------------------------------------------------------
__global__ void temp_kernel(const float* __restrict__ time_pos,
                            const float* __restrict__ freq_temporal,
                            const float* __restrict__ Wt,
                            const float* __restrict__ bt,
                            float* __restrict__ temp) {
    const int row = blockIdx.x;       // 0..15  (b*T + t)
    const int d   = threadIdx.x;      // 0..95
    const float p = time_pos[row];
    const float* __restrict__ wrow = Wt + d * DT;
    float sum = bt[d];
    #pragma unroll
    for (int j = 0; j < HALFT; ++j) {
        float s, c;
        sincosf(p * freq_temporal[j], &s, &c);
        sum = fmaf(c, wrow[2 * j], sum);
        sum = fmaf(s, wrow[2 * j + 1], sum);
    }
    temp[row * DH + d] = sum;
}

// ---------------------------------------------------------------------------
// Kernel 2: spatio rotation + temporal add, one thread per 3-elem block.
// Flat triple index i over (b, t, head, y, x, block) — all pow2 dims:
//   block = i & 31, x = (i>>5)&63, y = (i>>11)&63,
//   head = (i>>17)&7, t = (i>>20)&7, b = i>>23.
// Element offset = 3*i (block is innermost, d = 3*block).
// ---------------------------------------------------------------------------
__global__ __launch_bounds__(256) void rope_kernel(
        const float* __restrict__ q,
        const float* __restrict__ k,
        const float* __restrict__ spatial_pos,
        const float* __restrict__ freq_spatial,
        const float* __restrict__ temp,
        float* __restrict__ qo,
        float* __restrict__ ko) {
    const unsigned i = blockIdx.x * 256u + threadIdx.x;   // 0 .. 2^24-1

    const int blk  = i & 31;
    const int x    = (i >> 5)  & 63;
    const int y    = (i >> 11) & 63;
    const int head = (i >> 17) & 7;
    const int t    = (i >> 20) & 7;
    const int b    = (int)(i >> 23);

    // broadcast tables (L1/L2 resident)
    const int sp = ((b * HH + y) * WW + x) * 2;
    const float lat = spatial_pos[sp];
    const float lon = spatial_pos[sp + 1];
    const int fi = (head * NB + blk) * 2;
    const float fa = freq_spatial[fi];
    const float fb = freq_spatial[fi + 1];

    float sA, cA, sB, cB;
    __sincosf(lon * fa, &sA, &cA);   // angles are tiny (|A| < ~0.2) — fast path fine
    __sincosf(lat * fb, &sB, &cB);

    const int d = blk * 3;
    const float* __restrict__ trow = temp + (b * TT + t) * DH + d;
    const float t0 = trow[0], t1 = trow[1], t2 = trow[2];

    const size_t e = (size_t)i * 3u;
    const float q0 = q[e], q1 = q[e + 1], q2 = q[e + 2];
    const float k0 = k[e], k1 = k[e + 1], k2 = k[e + 2];

    // o0 =  x0*cA + x1*sA
    // o1 =  cB*u + x2*sB      where u = x1*cA - x0*sA
    // o2 = -sB*u + x2*cB
    const float uq = q1 * cA - q0 * sA;
    qo[e]     = q0 * cA + q1 * sA + t0;
    qo[e + 1] = cB * uq + q2 * sB + t1;
    qo[e + 2] = -sB * uq + q2 * cB + t2;

    const float uk = k1 * cA - k0 * sA;
    ko[e]     = k0 * cA + k1 * sA + t0;
    ko[e + 1] = cB * uk + k2 * sB + t1;
    ko[e + 2] = -sB * uk + k2 * cB + t2;
}

// ---------------------------------------------------------------------------
extern "C" void kernel_launch(void* const* d_in, const int* in_sizes, int n_in,
                              void* d_out, int out_size, void* d_ws, size_t ws_size,
                              hipStream_t stream) {
    const float* q             = (const float*)d_in[0];
    const float* k             = (const float*)d_in[1];
    const float* spatial_pos   = (const float*)d_in[2];
    const float* time_pos      = (const float*)d_in[3];
    const float* freq_spatial  = (const float*)d_in[4];
    const float* freq_temporal = (const float*)d_in[5];
    const float* Wt            = (const float*)d_in[6];
    const float* bt            = (const float*)d_in[7];

    float* out  = (float*)d_out;
    float* temp = (float*)d_ws;                       // 16*96*4 = 6144 B

    temp_kernel<<<BB * TT, DH, 0, stream>>>(time_pos, freq_temporal, Wt, bt, temp);

    const unsigned n_triples = BB * TT * NHEADS * HH * WW * NB;   // 2^24
    const size_t per_tensor  = (size_t)n_triples * 3u;            // 50,331,648
    rope_kernel<<<n_triples / 256, 256, 0, stream>>>(
        q, k, spatial_pos, freq_spatial, temp, out, out + per_tensor);
}